// Round 13
// baseline (100.409 us; speedup 1.0000x reference)
//
#include <hip/hip_runtime.h>

#define NB_CAT  8192
#define RANK    16
#define N_COLS  4
#define N_PAIRS 1048576

#define NSLICE      8                          // (col, rank-half), b128 rows
#define SLICE_ROWS  NB_CAT
#define SLICE_BYTES (SLICE_ROWS * 16)          // 128 KB
#define TBL_BYTES   ((size_t)NSLICE * SLICE_BYTES)   // 1 MB
#define LDS_BYTES   SLICE_BYTES
#define PART_BYTES  ((size_t)N_PAIRS * 4)      // 4 MB per partial
#define WS_NEED     (TBL_BYTES + NSLICE * PART_BYTES)  // 33 MB

typedef _Float16 half2_t __attribute__((ext_vector_type(2)));

#if defined(__has_builtin)
#if __has_builtin(__builtin_amdgcn_fdot2)
#define HAVE_FDOT2 1
#endif
#endif

__device__ __forceinline__ float dot8_f16(uint4 A, uint4 B, float acc) {
#ifdef HAVE_FDOT2
    acc = __builtin_amdgcn_fdot2(__builtin_bit_cast(half2_t, A.x), __builtin_bit_cast(half2_t, B.x), acc, false);
    acc = __builtin_amdgcn_fdot2(__builtin_bit_cast(half2_t, A.y), __builtin_bit_cast(half2_t, B.y), acc, false);
    acc = __builtin_amdgcn_fdot2(__builtin_bit_cast(half2_t, A.z), __builtin_bit_cast(half2_t, B.z), acc, false);
    acc = __builtin_amdgcn_fdot2(__builtin_bit_cast(half2_t, A.w), __builtin_bit_cast(half2_t, B.w), acc, false);
#else
    half2_t ax = __builtin_bit_cast(half2_t, A.x), bx = __builtin_bit_cast(half2_t, B.x);
    half2_t ay = __builtin_bit_cast(half2_t, A.y), by = __builtin_bit_cast(half2_t, B.y);
    half2_t az = __builtin_bit_cast(half2_t, A.z), bz = __builtin_bit_cast(half2_t, B.z);
    half2_t aw = __builtin_bit_cast(half2_t, A.w), bw = __builtin_bit_cast(half2_t, B.w);
    acc = fmaf((float)ax[0], (float)bx[0], acc); acc = fmaf((float)ax[1], (float)bx[1], acc);
    acc = fmaf((float)ay[0], (float)by[0], acc); acc = fmaf((float)ay[1], (float)by[1], acc);
    acc = fmaf((float)az[0], (float)bz[0], acc); acc = fmaf((float)az[1], (float)bz[1], acc);
    acc = fmaf((float)aw[0], (float)bw[0], acc); acc = fmaf((float)aw[1], (float)bw[1], acc);
#endif
    return acc;
}

__device__ __forceinline__ int comp4(const int4& v, int c) {
    return (c == 0) ? v.x : (c == 1) ? v.y : (c == 2) ? v.z : v.w;
}

// ---------- prep: fp32 cf -> fp16 table, layout [slice=(c,h)][cat] row = 16 B ----------
__global__ __launch_bounds__(256) void pack_f16_kernel(
    const float4* __restrict__ src, uint4* __restrict__ dst)
{
    const int g = blockIdx.x * 256 + threadIdx.x;   // slice*8192 + cat, 65536
    const int s = g >> 13;
    const int k = g & (NB_CAT - 1);
    const int c = s >> 1, h = s & 1;

    const float4 f0 = src[(c * NB_CAT + k) * 4 + h * 2];
    const float4 f1 = src[(c * NB_CAT + k) * 4 + h * 2 + 1];

    half2_t p0 = {(_Float16)f0.x, (_Float16)f0.y};
    half2_t p1 = {(_Float16)f0.z, (_Float16)f0.w};
    half2_t p2 = {(_Float16)f1.x, (_Float16)f1.y};
    half2_t p3 = {(_Float16)f1.z, (_Float16)f1.w};

    uint4 u;
    u.x = __builtin_bit_cast(unsigned int, p0);
    u.y = __builtin_bit_cast(unsigned int, p1);
    u.z = __builtin_bit_cast(unsigned int, p2);
    u.w = __builtin_bit_cast(unsigned int, p3);
    dst[g] = u;
}

// ---------- main: slice-resident, stage ONCE, zero mid-kernel barriers ----------
// 256 blocks x 1024 threads. slice = blockIdx>>5 (so all 8 slice-blocks of a
// chunk share an XCD: XCD = blockIdx%8 = chunk%8 -> idx lines L2-resident).
// Each block: stage its 128 KB slice, then stream 32768 pairs (32/thread):
// coalesced int4 idx loads + block-uniform col extract, 2 ds_read_b128 +
// 4 v_dot2 per pair, coalesced partial store. No atomics, no transpose.
__global__ __launch_bounds__(1024, 1) void IndexKernel_32238024524411_kernel(
    const int4*  __restrict__ x4,    // (N_PAIRS) int4
    const int4*  __restrict__ y4,
    const uint4* __restrict__ tbl,   // fp16 slice-major table in ws
    const float* __restrict__ stdv,  // (N_COLS, NB_CAT) fp32
    float*       __restrict__ part)  // (NSLICE, N_PAIRS) partials in ws
{
    extern __shared__ uint4 sh[];    // 8192 rows = 128 KB

    const int tid   = threadIdx.x;
    const int slice = blockIdx.x >> 5;   // 0..7
    const int chunk = blockIdx.x & 31;   // 0..31
    const int c     = slice >> 1;
    const int h     = slice & 1;

    // one-time stage (direct copy, compiler temps only — no demotable arrays)
    const uint4* src = tbl + (size_t)slice * SLICE_ROWS;
#pragma unroll
    for (int it = 0; it < 8; ++it) sh[tid + it * 1024] = src[tid + it * 1024];
    __syncthreads();   // the only barrier in the kernel

    const int   pbase = chunk * 32768 + tid;
    const float* sd   = stdv + (size_t)c * NB_CAT;
    float*       my   = part + (size_t)slice * N_PAIRS;

#pragma unroll
    for (int g = 0; g < 4; ++g) {
        int xi[8], yi[8];
#pragma unroll
        for (int j = 0; j < 8; ++j) {
            const int p = pbase + (g * 8 + j) * 1024;
            const int4 a = x4[p];
            const int4 b = y4[p];
            xi[j] = comp4(a, c);
            yi[j] = comp4(b, c);
        }
#pragma unroll
        for (int j = 0; j < 8; ++j) {
            float d = dot8_f16(sh[xi[j]], sh[yi[j]], 0.f);
            if (h == 0 && xi[j] == yi[j]) {
                const float s = sd[xi[j]];
                d = fmaf(s, s, d);
            }
            my[pbase + (g * 8 + j) * 1024] = d;
        }
    }
}

// ---------- reduce: out[p] = sum over 8 slice-partials ----------
__global__ __launch_bounds__(256) void reduce8_kernel(
    const float4* __restrict__ part, float4* __restrict__ out)
{
    const int i = blockIdx.x * 256 + threadIdx.x;   // 262144 float4s
    float4 s = part[i];
#pragma unroll
    for (int k = 1; k < NSLICE; ++k) {
        const float4 v = part[(size_t)k * (N_PAIRS / 4) + i];
        s.x += v.x; s.y += v.y; s.z += v.z; s.w += v.w;
    }
    out[i] = s;
}

// ---------- fallback (fp32 direct gather, R3 structure) if ws too small ----------
__global__ __launch_bounds__(256) void fallback_kernel(
    const int* __restrict__ x, const int* __restrict__ y,
    const float4* __restrict__ cf, const float* __restrict__ stdv,
    float* __restrict__ out)
{
    const int tid = threadIdx.x;
    const int q = tid & 15, gi = tid >> 4, c = q >> 2, s = q & 3;
    const int p0 = blockIdx.x * 32 + gi, p1 = p0 + 16;
    const int rb = c * NB_CAT;
    const int xi0 = x[p0*4+c], yi0 = y[p0*4+c], xi1 = x[p1*4+c], yi1 = y[p1*4+c];
    const float4 a0 = cf[(size_t)(rb+xi0)*4 + s], b0 = cf[(size_t)(rb+yi0)*4 + s];
    const float4 a1 = cf[(size_t)(rb+xi1)*4 + s], b1 = cf[(size_t)(rb+yi1)*4 + s];
    float v0 = a0.x*b0.x; v0 = fmaf(a0.y,b0.y,v0); v0 = fmaf(a0.z,b0.z,v0); v0 = fmaf(a0.w,b0.w,v0);
    float v1 = a1.x*b1.x; v1 = fmaf(a1.y,b1.y,v1); v1 = fmaf(a1.z,b1.z,v1); v1 = fmaf(a1.w,b1.w,v1);
    if (s == 0 && xi0 == yi0) { float sd = stdv[rb+xi0]; v0 = fmaf(sd,sd,v0); }
    if (s == 0 && xi1 == yi1) { float sd = stdv[rb+xi1]; v1 = fmaf(sd,sd,v1); }
    int t;
    t = __builtin_amdgcn_update_dpp(0, __float_as_int(v0), 0xB1, 0xF, 0xF, true); v0 += __int_as_float(t);
    t = __builtin_amdgcn_update_dpp(0, __float_as_int(v0), 0x4E, 0xF, 0xF, true); v0 += __int_as_float(t);
    t = __builtin_amdgcn_update_dpp(0, __float_as_int(v0), 0x141,0xF, 0xF, true); v0 += __int_as_float(t);
    t = __builtin_amdgcn_update_dpp(0, __float_as_int(v0), 0x128,0xF, 0xF, true); v0 += __int_as_float(t);
    t = __builtin_amdgcn_update_dpp(0, __float_as_int(v1), 0xB1, 0xF, 0xF, true); v1 += __int_as_float(t);
    t = __builtin_amdgcn_update_dpp(0, __float_as_int(v1), 0x4E, 0xF, 0xF, true); v1 += __int_as_float(t);
    t = __builtin_amdgcn_update_dpp(0, __float_as_int(v1), 0x141,0xF, 0xF, true); v1 += __int_as_float(t);
    t = __builtin_amdgcn_update_dpp(0, __float_as_int(v1), 0x128,0xF, 0xF, true); v1 += __int_as_float(t);
    if (q == 0) { out[p0] = v0; out[p1] = v1; }
}

extern "C" void kernel_launch(void* const* d_in, const int* in_sizes, int n_in,
                              void* d_out, int out_size, void* d_ws, size_t ws_size,
                              hipStream_t stream) {
    const int*   x    = (const int*)d_in[0];
    const int*   y    = (const int*)d_in[1];
    const float* cf   = (const float*)d_in[2];
    const float* stdv = (const float*)d_in[3];
    float*       out  = (float*)d_out;

    if (ws_size < WS_NEED) {
        fallback_kernel<<<N_PAIRS / 32, 256, 0, stream>>>(
            x, y, (const float4*)cf, stdv, out);
        return;
    }

    (void)hipFuncSetAttribute(
        reinterpret_cast<const void*>(&IndexKernel_32238024524411_kernel),
        hipFuncAttributeMaxDynamicSharedMemorySize, LDS_BYTES);

    uint4* tbl  = (uint4*)d_ws;
    float* part = (float*)((char*)d_ws + TBL_BYTES);   // (NSLICE, N_PAIRS)

    pack_f16_kernel<<<NSLICE * NB_CAT / 256, 256, 0, stream>>>(
        (const float4*)cf, tbl);

    IndexKernel_32238024524411_kernel<<<NSLICE * 32, 1024, LDS_BYTES, stream>>>(
        (const int4*)x, (const int4*)y, tbl, stdv, part);

    reduce8_kernel<<<N_PAIRS / 4 / 256, 256, 0, stream>>>(
        (const float4*)part, (float4*)out);
}

// Round 14
// 95.509 us; speedup vs baseline: 1.0513x; 1.0513x over previous
//
#include <hip/hip_runtime.h>

#define NB_CAT  8192
#define RANK    16
#define N_COLS  4
#define N_PAIRS 1048576

#define NSLICE      8                          // (col, rank-half), b128 rows
#define SLICE_ROWS  NB_CAT
#define SLICE_BYTES (SLICE_ROWS * 16)          // 128 KB
#define TBL_BYTES   ((size_t)NSLICE * SLICE_BYTES)   // 1 MB
#define LDS_BYTES   SLICE_BYTES                // single 128 KB buffer

typedef _Float16 half2_t __attribute__((ext_vector_type(2)));

#if defined(__has_builtin)
#if __has_builtin(__builtin_amdgcn_fdot2)
#define HAVE_FDOT2 1
#endif
#endif

__device__ __forceinline__ float dot8_f16(uint4 A, uint4 B, float acc) {
#ifdef HAVE_FDOT2
    acc = __builtin_amdgcn_fdot2(__builtin_bit_cast(half2_t, A.x), __builtin_bit_cast(half2_t, B.x), acc, false);
    acc = __builtin_amdgcn_fdot2(__builtin_bit_cast(half2_t, A.y), __builtin_bit_cast(half2_t, B.y), acc, false);
    acc = __builtin_amdgcn_fdot2(__builtin_bit_cast(half2_t, A.z), __builtin_bit_cast(half2_t, B.z), acc, false);
    acc = __builtin_amdgcn_fdot2(__builtin_bit_cast(half2_t, A.w), __builtin_bit_cast(half2_t, B.w), acc, false);
#else
    half2_t ax = __builtin_bit_cast(half2_t, A.x), bx = __builtin_bit_cast(half2_t, B.x);
    half2_t ay = __builtin_bit_cast(half2_t, A.y), by = __builtin_bit_cast(half2_t, B.y);
    half2_t az = __builtin_bit_cast(half2_t, A.z), bz = __builtin_bit_cast(half2_t, B.z);
    half2_t aw = __builtin_bit_cast(half2_t, A.w), bw = __builtin_bit_cast(half2_t, B.w);
    acc = fmaf((float)ax[0], (float)bx[0], acc); acc = fmaf((float)ax[1], (float)bx[1], acc);
    acc = fmaf((float)ay[0], (float)by[0], acc); acc = fmaf((float)ay[1], (float)by[1], acc);
    acc = fmaf((float)az[0], (float)bz[0], acc); acc = fmaf((float)az[1], (float)bz[1], acc);
    acc = fmaf((float)aw[0], (float)bw[0], acc); acc = fmaf((float)aw[1], (float)bw[1], acc);
#endif
    return acc;
}

template <int C> __device__ __forceinline__ int comp(const int4& v) {
    if (C == 0) return v.x;
    if (C == 1) return v.y;
    if (C == 2) return v.z;
    return v.w;
}

// ---------- prep: fp32 cf -> fp16 table, layout [slice=(c,h)][cat] row = 16 B ----------
__global__ __launch_bounds__(256) void pack_f16_kernel(
    const float4* __restrict__ src, uint4* __restrict__ dst)
{
    const int g = blockIdx.x * 256 + threadIdx.x;   // slice*8192 + cat, 65536
    const int s = g >> 13;
    const int k = g & (NB_CAT - 1);
    const int c = s >> 1, h = s & 1;

    const float4 f0 = src[(c * NB_CAT + k) * 4 + h * 2];
    const float4 f1 = src[(c * NB_CAT + k) * 4 + h * 2 + 1];

    half2_t p0 = {(_Float16)f0.x, (_Float16)f0.y};
    half2_t p1 = {(_Float16)f0.z, (_Float16)f0.w};
    half2_t p2 = {(_Float16)f1.x, (_Float16)f1.y};
    half2_t p3 = {(_Float16)f1.z, (_Float16)f1.w};

    uint4 u;
    u.x = __builtin_bit_cast(unsigned int, p0);
    u.y = __builtin_bit_cast(unsigned int, p1);
    u.z = __builtin_bit_cast(unsigned int, p2);
    u.w = __builtin_bit_cast(unsigned int, p3);
    dst[g] = u;
}

// ---------- main: all 4 cols/block, b128 rows, 8 phases, named-reg prefetch ----------
// 256 blocks x 1024 threads, 128 KB dyn LDS (single buffer). 4096 pairs/block
// (4/thread), ONE coalesced int4 idx load, direct out write — no partials, no
// reduce kernel, no idx re-read. Phase s (c=s>>1, h=s&1): prefetch slice s+1
// into 8 NAMED uint4 regs (in flight across raw lgkm-only barriers), compute
// (2 ds_read_b128 + 4 v_dot2 per pair), barrier, ds_write, barrier.
__global__ __launch_bounds__(1024, 1) void IndexKernel_32238024524411_kernel(
    const int4*  __restrict__ x4,    // (N_PAIRS) int4
    const int4*  __restrict__ y4,
    const uint4* __restrict__ tbl,   // fp16 slice-major table in ws
    const float* __restrict__ stdv,  // (N_COLS, NB_CAT) fp32
    float*       __restrict__ out)
{
    extern __shared__ uint4 sh[];    // 8192 rows = 128 KB

    const int tid  = threadIdx.x;
    const int base = blockIdx.x * 4096 + tid;

    // coalesced one-time index loads
    int4 xv[4], yv[4];
#pragma unroll
    for (int j = 0; j < 4; ++j) {
        xv[j] = x4[base + j * 1024];
        yv[j] = y4[base + j * 1024];
    }

    float acc[4] = {0.f, 0.f, 0.f, 0.f};

    // diagonal std^2 pre-pass (rare; keeps phase loop free of global vmem)
#pragma unroll
    for (int j = 0; j < 4; ++j) {
        const int4 a = xv[j], b = yv[j];
        if (a.x == b.x) { const float s = stdv[0 * NB_CAT + a.x]; acc[j] = fmaf(s, s, acc[j]); }
        if (a.y == b.y) { const float s = stdv[1 * NB_CAT + a.y]; acc[j] = fmaf(s, s, acc[j]); }
        if (a.z == b.z) { const float s = stdv[2 * NB_CAT + a.z]; acc[j] = fmaf(s, s, acc[j]); }
        if (a.w == b.w) { const float s = stdv[3 * NB_CAT + a.w]; acc[j] = fmaf(s, s, acc[j]); }
    }

    // stage slice 0 directly (compiler temps only)
#pragma unroll
    for (int it = 0; it < 8; ++it) sh[tid + it * 1024] = tbl[tid + it * 1024];
    asm volatile("s_waitcnt lgkmcnt(0)" ::: "memory");
    __builtin_amdgcn_s_barrier();
    asm volatile("" ::: "memory");

    // named prefetch registers — no array, guaranteed SROA (R10 lesson)
    uint4 t0, t1, t2, t3, t4, t5, t6, t7;

#define PHASE(S)                                                               \
    {                                                                          \
        constexpr int s = (S);                                                 \
        if (s < NSLICE - 1) {                                                  \
            const uint4* nsrc = tbl + (size_t)(s + 1) * SLICE_ROWS;            \
            t0 = nsrc[tid];             t1 = nsrc[tid + 1024];                 \
            t2 = nsrc[tid + 2 * 1024];  t3 = nsrc[tid + 3 * 1024];             \
            t4 = nsrc[tid + 4 * 1024];  t5 = nsrc[tid + 5 * 1024];             \
            t6 = nsrc[tid + 6 * 1024];  t7 = nsrc[tid + 7 * 1024];             \
        }                                                                      \
        asm volatile("" ::: "memory");                                         \
        _Pragma("unroll")                                                      \
        for (int j = 0; j < 4; ++j) {                                          \
            const int a = comp<(s >> 1)>(xv[j]);                               \
            const int b = comp<(s >> 1)>(yv[j]);                               \
            acc[j] = dot8_f16(sh[a], sh[b], acc[j]);                           \
        }                                                                      \
        if (s < NSLICE - 1) {                                                  \
            asm volatile("s_waitcnt lgkmcnt(0)" ::: "memory");                 \
            __builtin_amdgcn_s_barrier();                                      \
            asm volatile("" ::: "memory");                                     \
            sh[tid]            = t0;  sh[tid + 1024]     = t1;                 \
            sh[tid + 2 * 1024] = t2;  sh[tid + 3 * 1024] = t3;                 \
            sh[tid + 4 * 1024] = t4;  sh[tid + 5 * 1024] = t5;                 \
            sh[tid + 6 * 1024] = t6;  sh[tid + 7 * 1024] = t7;                 \
            asm volatile("s_waitcnt lgkmcnt(0)" ::: "memory");                 \
            __builtin_amdgcn_s_barrier();                                      \
            asm volatile("" ::: "memory");                                     \
        }                                                                      \
    }

    PHASE(0) PHASE(1) PHASE(2) PHASE(3)
    PHASE(4) PHASE(5) PHASE(6) PHASE(7)
#undef PHASE

#pragma unroll
    for (int j = 0; j < 4; ++j) {
        out[base + j * 1024] = acc[j];
    }
}

// ---------- fallback (fp32 direct gather, R3 structure) if ws too small ----------
__global__ __launch_bounds__(256) void fallback_kernel(
    const int* __restrict__ x, const int* __restrict__ y,
    const float4* __restrict__ cf, const float* __restrict__ stdv,
    float* __restrict__ out)
{
    const int tid = threadIdx.x;
    const int q = tid & 15, gi = tid >> 4, c = q >> 2, s = q & 3;
    const int p0 = blockIdx.x * 32 + gi, p1 = p0 + 16;
    const int rb = c * NB_CAT;
    const int xi0 = x[p0*4+c], yi0 = y[p0*4+c], xi1 = x[p1*4+c], yi1 = y[p1*4+c];
    const float4 a0 = cf[(size_t)(rb+xi0)*4 + s], b0 = cf[(size_t)(rb+yi0)*4 + s];
    const float4 a1 = cf[(size_t)(rb+xi1)*4 + s], b1 = cf[(size_t)(rb+yi1)*4 + s];
    float v0 = a0.x*b0.x; v0 = fmaf(a0.y,b0.y,v0); v0 = fmaf(a0.z,b0.z,v0); v0 = fmaf(a0.w,b0.w,v0);
    float v1 = a1.x*b1.x; v1 = fmaf(a1.y,b1.y,v1); v1 = fmaf(a1.z,b1.z,v1); v1 = fmaf(a1.w,b1.w,v1);
    if (s == 0 && xi0 == yi0) { float sd = stdv[rb+xi0]; v0 = fmaf(sd,sd,v0); }
    if (s == 0 && xi1 == yi1) { float sd = stdv[rb+xi1]; v1 = fmaf(sd,sd,v1); }
    int t;
    t = __builtin_amdgcn_update_dpp(0, __float_as_int(v0), 0xB1, 0xF, 0xF, true); v0 += __int_as_float(t);
    t = __builtin_amdgcn_update_dpp(0, __float_as_int(v0), 0x4E, 0xF, 0xF, true); v0 += __int_as_float(t);
    t = __builtin_amdgcn_update_dpp(0, __float_as_int(v0), 0x141,0xF, 0xF, true); v0 += __int_as_float(t);
    t = __builtin_amdgcn_update_dpp(0, __float_as_int(v0), 0x128,0xF, 0xF, true); v0 += __int_as_float(t);
    t = __builtin_amdgcn_update_dpp(0, __float_as_int(v1), 0xB1, 0xF, 0xF, true); v1 += __int_as_float(t);
    t = __builtin_amdgcn_update_dpp(0, __float_as_int(v1), 0x4E, 0xF, 0xF, true); v1 += __int_as_float(t);
    t = __builtin_amdgcn_update_dpp(0, __float_as_int(v1), 0x141,0xF, 0xF, true); v1 += __int_as_float(t);
    t = __builtin_amdgcn_update_dpp(0, __float_as_int(v1), 0x128,0xF, 0xF, true); v1 += __int_as_float(t);
    if (q == 0) { out[p0] = v0; out[p1] = v1; }
}

extern "C" void kernel_launch(void* const* d_in, const int* in_sizes, int n_in,
                              void* d_out, int out_size, void* d_ws, size_t ws_size,
                              hipStream_t stream) {
    const int*   x    = (const int*)d_in[0];
    const int*   y    = (const int*)d_in[1];
    const float* cf   = (const float*)d_in[2];
    const float* stdv = (const float*)d_in[3];
    float*       out  = (float*)d_out;

    if (ws_size < TBL_BYTES) {
        fallback_kernel<<<N_PAIRS / 32, 256, 0, stream>>>(
            x, y, (const float4*)cf, stdv, out);
        return;
    }

    (void)hipFuncSetAttribute(
        reinterpret_cast<const void*>(&IndexKernel_32238024524411_kernel),
        hipFuncAttributeMaxDynamicSharedMemorySize, LDS_BYTES);

    pack_f16_kernel<<<NSLICE * NB_CAT / 256, 256, 0, stream>>>(
        (const float4*)cf, (uint4*)d_ws);

    IndexKernel_32238024524411_kernel<<<N_PAIRS / 4096, 1024, LDS_BYTES, stream>>>(
        (const int4*)x, (const int4*)y, (const uint4*)d_ws, stdv, out);
}